// Round 14
// baseline (485.406 us; speedup 1.0000x reference)
//
#include <hip/hip_runtime.h>
#include <cstdint>
#include <cstddef>

// B=10, Hi=Wi=64, C=64, M=8, Hb=Wb=128, U=64.
// Pipeline per b-half: tr_if -> conv1_m (fp32-accurate 3-way bf16 split,
// 32x32x16 MFMA + 16-ch quad-pass LDS, 38KB -> 4 blocks/CU) -> conv2_m ->
// compose_v4. h1g in d_out upper half. Round-13 fix: D-layout probe verdict
// carried in a REGISTER (the double-declared __shared__ swzf was UB).

typedef __attribute__((ext_vector_type(8))) short short8;
typedef __attribute__((ext_vector_type(4))) float f32x4;
typedef __attribute__((ext_vector_type(16))) float f32x16;

__device__ __forceinline__ unsigned short f2bf(float x) {
  union { float f; unsigned int u; } v; v.f = x;
  unsigned int r = (v.u + 0x7FFFu + ((v.u >> 16) & 1u)) >> 16;  // RNE
  return (unsigned short)r;
}
__device__ __forceinline__ float bf2f(unsigned short h) {
  union { unsigned int u; float f; } v; v.u = ((unsigned int)h) << 16;
  return v.f;
}
__device__ __forceinline__ void split3(float v, unsigned short& h,
                                       unsigned short& m, unsigned short& l) {
  h = f2bf(v);
  float r1 = v - bf2f(h);
  m = f2bf(r1);
  float r2 = r1 - bf2f(m);
  l = f2bf(r2);
}

// ---------------------------------------------------------------------------
// prep_w32: w [3,3,64,64] HWIO fp32 -> 3 bf16 planes ordered for 32x32x16:
// wB[s][((kq*2+ut)*64+lane)*8+i], k = kq*16 + (lane>>5)*8 + i (kq in [0,36)),
// tap = k>>6, c = k&63, u = ut*32 + (lane&31). Plane stride 36864 elems.
// A and B share this (lane,i)->k map -> result invariant to HW k-wiring.
// ---------------------------------------------------------------------------
__global__ void prep_w32(const float* __restrict__ w, unsigned short* __restrict__ wB)
{
  int idx = blockIdx.x * 256 + threadIdx.x;
  if (idx >= 36864) return;
  int i = idx & 7;
  int lane = (idx >> 3) & 63;
  int ut = (idx >> 9) & 1;
  int kq = idx >> 10;
  int k = kq * 16 + ((lane >> 5) << 3) + i;
  int u = ut * 32 + (lane & 31);
  int tap = k >> 6, c = k & 63;
  float v = w[((size_t)(tap * 64 + c)) * 64 + u];
  unsigned short h, m, l;
  split3(v, h, m, l);
  wB[idx] = h;
  wB[36864 + idx] = m;
  wB[73728 + idx] = l;
}

// ---------------------------------------------------------------------------
// tr_if: IF half (5 b's) [b,y,x,c,m] -> TIF [img=bb*8+m][y][x][c] fp32.
// (proven rounds 3/11/12)
// ---------------------------------------------------------------------------
__global__ __launch_bounds__(256) void tr_if(const float* __restrict__ IFh,
                                             float* __restrict__ TIF)
{
  const int idx = blockIdx.x * 256 + threadIdx.x;   // 5*64*64*64 = 1,310,720
  const int c = idx & 63;
  const int x = (idx >> 6) & 63;
  const int y = (idx >> 12) & 63;
  const int bb = idx >> 18;
  const float* p = IFh + (size_t)idx * 8;
  float4 v0 = *(const float4*)p;
  float4 v1 = *(const float4*)(p + 4);
  float mv[8] = {v0.x, v0.y, v0.z, v0.w, v1.x, v1.y, v1.z, v1.w};
  #pragma unroll
  for (int m = 0; m < 8; ++m)
    TIF[((size_t)(bb * 8 + m) * 4096 + y * 64 + x) * 64 + c] = mv[m];
}

// ---------------------------------------------------------------------------
// conv1_m: merged instance+bg conv1 for one half (hh = 0/1). Grid = 960.
// Wave = 64 px x 64 u as 2x2 tiles of 32x32; 4 passes over 16-ch quarters
// (LDS 38,016 B -> 4 blocks/CU). 6-product split accumulation, per-acc
// product order unchanged. Register-carried runtime D-layout probe.
// ---------------------------------------------------------------------------
__global__ __launch_bounds__(256, 4) void conv1_m(const float* __restrict__ TIF,
    const float* __restrict__ BG,
    const unsigned short* __restrict__ wBi, const unsigned short* __restrict__ wBb,
    const float* __restrict__ b1i, const float* __restrict__ b1b,
    float* __restrict__ h1i, float* __restrict__ h1g, int hh)
{
  __shared__ __align__(16) char lds[38016];   // 3 * 12672

  const int tid = threadIdx.x;
  const int bid = blockIdx.x;
  const bool inst = (bid < 640);

  int H, W, imgL, xt, rg;
  const unsigned short* wB;
  const float* bias;
  const float* srcimg;
  float* dst;
  if (inst) {
    H = 64; W = 64;
    imgL = bid >> 4; rg = bid & 15; xt = 0;
    wB = wBi; bias = b1i; dst = h1i;
    srcimg = TIF + (size_t)imgL * 262144;
  } else {
    const int bb = bid - 640;
    H = 128; W = 128;
    xt = bb & 1;
    const int t2 = bb >> 1;
    rg = t2 & 31; imgL = t2 >> 5;
    wB = wBb; bias = b1b; dst = h1g;
    srcimg = BG + (size_t)(hh * 5 + imgL) * 1048576;
  }
  const int yb = rg << 2;
  const int xb = xt << 6;
  const int wave = tid >> 6, lane = tid & 63;
  const int l31 = lane & 31, cg8 = lane >> 5;

  f32x16 zz;
  #pragma unroll
  for (int i = 0; i < 16; ++i) zz[i] = 0.f;

  // ---- D-layout probe (asymmetric), verdict in a REGISTER.
  // A[m][5]=m+1 (lanes cg8==0), B[5][n]=(n+1)^2. At (lane=2,reg=0):
  // guide convention (col=lane&31,row=(reg&3)+8(reg>>2)+4(lane>>5)) -> 9;
  // swapped -> 3.
  bool swapped;
  {
    short8 pa = {0,0,0,0,0,0,0,0}, pb = {0,0,0,0,0,0,0,0};
    if (cg8 == 0) {
      pa[5] = (short)f2bf((float)(l31 + 1));
      pb[5] = (short)f2bf((float)((l31 + 1) * (l31 + 1)));
    }
    f32x16 pd = __builtin_amdgcn_mfma_f32_32x32x16_bf16(pa, pb, zz, 0, 0, 0);
    const float d2 = __shfl(pd[0], 2, 64);
    swapped = (d2 < 6.0f);
  }

  f32x16 acc[2][2];   // [pxt][ut]
  #pragma unroll
  for (int i = 0; i < 2; ++i)
    #pragma unroll
    for (int j = 0; j < 2; ++j)
      acc[i][j] = zz;

  const short8* wBp = (const short8*)wB;   // plane stride 4608 short8

  for (int q = 0; q < 4; ++q) {
    if (q) __syncthreads();
    // ---- stage + split: rows yb-1..yb+4, x xb-1..xb+64, 16-ch quarter
    for (int e = tid; e < 792; e += 256) {
      const int cg = e & 1;          // 8-ch granule within quarter
      const int q2 = e >> 1;
      const int xi = q2 % 66;
      const int r = q2 / 66;
      const int gy = yb + r - 1;
      const int gx = xb + xi - 1;
      float v[8] = {0.f, 0.f, 0.f, 0.f, 0.f, 0.f, 0.f, 0.f};
      if (gy >= 0 && gy < H && gx >= 0 && gx < W) {
        const float* p = srcimg + ((size_t)gy * W + gx) * 64 + q * 16 + cg * 8;
        float4 a = *(const float4*)p;
        float4 bq = *(const float4*)(p + 4);
        v[0] = a.x; v[1] = a.y; v[2] = a.z; v[3] = a.w;
        v[4] = bq.x; v[5] = bq.y; v[6] = bq.z; v[7] = bq.w;
      }
      short8 ph, pm, pl;
      #pragma unroll
      for (int j = 0; j < 8; ++j) {
        unsigned short h2, mi, l2;
        split3(v[j], h2, mi, l2);
        ph[j] = (short)h2; pm[j] = (short)mi; pl[j] = (short)l2;
      }
      const int wbase = ((r * 2 + cg) * 66 + xi) << 4;
      *(short8*)&lds[wbase] = ph;
      *(short8*)&lds[wbase + 12672] = pm;
      *(short8*)&lds[wbase + 25344] = pl;
    }
    __syncthreads();

    // ---- K-loop over 9 taps (kq = tap*4 + q)
    for (int tap = 0; tap < 9; ++tap) {
      const int dy = tap / 3, dx = tap % 3;
      const int kq = tap * 4 + q;
      short8 a[2][3];
      #pragma unroll
      for (int pxt = 0; pxt < 2; ++pxt) {
        const int abase = (((wave + dy) * 2 + cg8) * 66 + (pxt * 32 + l31 + dx)) << 4;
        #pragma unroll
        for (int pl = 0; pl < 3; ++pl)
          a[pxt][pl] = *(const short8*)&lds[abase + pl * 12672];
      }
      #pragma unroll
      for (int ut = 0; ut < 2; ++ut) {
        const int bi = (kq * 2 + ut) * 64 + lane;
        short8 bfr[3];
        bfr[0] = wBp[bi];
        bfr[1] = wBp[4608 + bi];
        bfr[2] = wBp[9216 + bi];
        // per-acc product order: (a0,b0)(a0,b1)(a1,b0)(a0,b2)(a2,b0)(a1,b1)
        #pragma unroll
        for (int p = 0; p < 6; ++p) {
          const int PA[6] = {0, 0, 1, 0, 2, 1};
          const int PB[6] = {0, 1, 0, 2, 0, 1};
          const int pa = PA[p], pb = PB[p];
          #pragma unroll
          for (int pxt = 0; pxt < 2; ++pxt)
            acc[pxt][ut] = __builtin_amdgcn_mfma_f32_32x32x16_bf16(
                a[pxt][pa], bfr[pb], acc[pxt][ut], 0, 0, 0);
        }
      }
    }
  }

  // ---- epilogue: D col=lane&31 (=u), row=(reg&3)+8*(reg>>2)+4*(lane>>5)
  // (=px within 32-tile); probe corrects if swapped. y = yb+wave.
  const int y = yb + wave;
  #pragma unroll
  for (int ut = 0; ut < 2; ++ut) {
    #pragma unroll
    for (int pxt = 0; pxt < 2; ++pxt) {
      #pragma unroll
      for (int reg = 0; reg < 16; ++reg) {
        const int rloc = (reg & 3) + 8 * (reg >> 2) + 4 * cg8;
        const int pxl = swapped ? l31 : rloc;
        const int ul  = swapped ? rloc : l31;
        const int px = xb + pxt * 32 + pxl;
        const int u = ut * 32 + ul;
        dst[((size_t)(imgL * H + y) * W + px) * 64 + u] =
            fmaxf(acc[pxt][ut][reg] + bias[u], 0.f);
      }
    }
  }
}

// ---------------------------------------------------------------------------
// conv2_m: merged instance+bg conv2 for one half. Grid = 960. (proven)
// ---------------------------------------------------------------------------
__global__ __launch_bounds__(256) void conv2_m(const float* __restrict__ h1i,
    const float* __restrict__ h1g,
    const float* __restrict__ w2i, const float* __restrict__ w2b,
    const float* __restrict__ b2i, const float* __restrict__ b2b,
    float* __restrict__ instw, float* __restrict__ bgw, int hh)
{
  const int RS = 24;
  const int CS = 18 * 24 + 1;  // 433
  __shared__ float s[32 * (18 * 24 + 1)];
  __shared__ float wsm[576];

  const int tid = threadIdx.x;
  const int bid = blockIdx.x;
  const bool inst = (bid < 640);

  int H, W, n, xt, yt;
  const float* hsrc;
  const float* w2;
  const float* b2;
  float* dst;
  if (inst) {
    H = 64; W = 64;
    n = bid >> 4;
    const int t = bid & 15;
    xt = t & 3; yt = t >> 2;
    hsrc = h1i; w2 = w2i; b2 = b2i;
    dst = instw + (size_t)(hh * 40 + n) * 4096;
  } else {
    const int bb = bid - 640;
    H = 128; W = 128;
    n = bb >> 6;
    const int t = bb & 63;
    xt = t & 7; yt = t >> 3;
    hsrc = h1g; w2 = w2b; b2 = b2b;
    dst = bgw + (size_t)(hh * 5 + n) * 16384;
  }
  const int xb = xt << 4, yb = yt << 4;
  const int tx = tid & 15, ty = tid >> 4;

  for (int e = tid; e < 576; e += 256) wsm[e] = w2[e];

  float acc = 0.f;
  for (int cc = 0; cc < 2; ++cc) {
    const int c0 = cc << 5;
    if (cc) __syncthreads();
    for (int e = tid; e < 18 * 18 * 32; e += 256) {
      int c = e & 31;
      int p = e >> 5;
      int xx = p % 18;
      int yy = p / 18;
      int gy = yb + yy - 1, gx = xb + xx - 1;
      float v = 0.f;
      if (gy >= 0 && gy < H && gx >= 0 && gx < W)
        v = hsrc[((size_t)(n * H + gy) * W + gx) * 64 + c0 + c];
      s[c * CS + yy * RS + xx] = v;
    }
    __syncthreads();
    for (int c = 0; c < 32; ++c) {
      const float* sp = &s[c * CS + ty * RS + tx];
      const float* wp = &wsm[c0 + c];
      #pragma unroll
      for (int dy = 0; dy < 3; ++dy)
        #pragma unroll
        for (int dx = 0; dx < 3; ++dx)
          acc += sp[dy * RS + dx] * wp[(dy * 3 + dx) * 64];
    }
  }
  dst[(size_t)(yb + ty) * W + xb + tx] = fmaxf(acc + b2[0], 0.f);
}

// ---------------------------------------------------------------------------
// compose_v4: wave = 1 pixel; phase 0 = per-m param chains on lanes 0..7
// (LDS table); phase 1 = coalesced taps from TIF + wave-uniform skip. (proven)
// ---------------------------------------------------------------------------
__global__ __launch_bounds__(256) void compose_v4(const float* __restrict__ TIF,
    const float* __restrict__ bg, const float* __restrict__ bbox,
    const int* __restrict__ objn, const float* __restrict__ instw,
    const float* __restrict__ bgw, float* __restrict__ out, int hh)
{
  __shared__ __align__(16) float P[4][8][8];

  const int tid = threadIdx.x;
  const int lane = tid & 63;
  const int wave = tid >> 6;
  const int c = lane;
  const int pid = hh * 81920 + blockIdx.x * 4 + wave;
  const int b = pid >> 14;
  const int rem = pid & 16383;
  const int hhp = rem >> 7;
  const int www = rem & 127;

  if (lane < 8) {
    const int m = lane;
    const float y0b = bbox[b * 32 + m];
    const float y1b = bbox[b * 32 + 8 + m];
    const float x0b = bbox[b * 32 + 16 + m];
    const float x1b = bbox[b * 32 + 24 + m];
    const float ysz = floorf(128.f * (y1b - y0b));
    const float xsz = floorf(128.f * (x1b - x0b));
    const float yf = floorf(128.f * y0b);
    const float xf = floorf(128.f * x0b);
    const float ly = (float)hhp - yf;
    const float lx = (float)www - xf;
    const bool valid = (m < objn[b]) && (ly >= 0.f) && (ly < ysz)
                       && (lx >= 0.f) && (lx < xsz);
    float sy = (ly + 0.5f) * 64.f / fmaxf(ysz, 1.f) - 0.5f;
    float sx = (lx + 0.5f) * 64.f / fmaxf(xsz, 1.f) - 0.5f;
    sy = fminf(fmaxf(sy, 0.f), 63.f);
    sx = fminf(fmaxf(sx, 0.f), 63.f);
    const int y0i = (int)floorf(sy);
    const int x0i = (int)floorf(sx);
    const int y1i = min(y0i + 1, 63);
    const int x1i = min(x0i + 1, 63);
    const float wy = sy - (float)y0i;
    const float wx = sx - (float)x0i;
    const float omwx = 1.f - wx, omwy = 1.f - wy;

    const float* iw = instw + (size_t)(b * 8 + m) * 4096;
    const float v00 = iw[y0i * 64 + x0i];
    const float v01 = iw[y0i * 64 + x1i];
    const float v10 = iw[y1i * 64 + x0i];
    const float v11 = iw[y1i * 64 + x1i];
    const float rwv = (v00 * omwx + v01 * wx) * omwy + (v10 * omwx + v11 * wx) * wy;
    const bool on = valid && (rwv > 0.f);
    const float e = on ? expf(rwv) : 0.f;

    P[wave][m][0] = e;
    P[wave][m][1] = wx;
    P[wave][m][2] = wy;
    P[wave][m][3] = (float)(y0i * 4096 + x0i * 64);
    P[wave][m][4] = (float)(y0i * 4096 + x1i * 64);
    P[wave][m][5] = (float)(y1i * 4096 + x0i * 64);
    P[wave][m][6] = (float)(y1i * 4096 + x1i * 64);
    P[wave][m][7] = 0.f;
  }
  __syncthreads();

  const float ebg = expf(bgw[pid]);
  const float bgc = bg[(size_t)pid * 64 + c];
  float denom = ebg;
  float acc = ebg * bgc;
  const float* fb = TIF + (size_t)(b - hh * 5) * 8 * 262144 + c;

  #pragma unroll
  for (int m = 0; m < 8; ++m) {
    const float4 pa = *(const float4*)&P[wave][m][0];
    const float4 pb = *(const float4*)&P[wave][m][4];
    const float e = pa.x;
    denom += e;
    if (e != 0.f) {
      const float* fm = fb + (size_t)m * 262144;
      const float t00 = fm[(int)pa.w];
      const float t01 = fm[(int)pb.x];
      const float t10 = fm[(int)pb.y];
      const float t11 = fm[(int)pb.z];
      const float wx = pa.y, wy = pa.z;
      const float omwx = 1.f - wx, omwy = 1.f - wy;
      const float bil = (t00 * omwx + t01 * wx) * omwy + (t10 * omwx + t11 * wx) * wy;
      acc += e * bil;
    }
  }
  out[(size_t)pid * 64 + c] = acc / denom;
}

// ---------------------------------------------------------------------------
extern "C" void kernel_launch(void* const* d_in, const int* in_sizes, int n_in,
                              void* d_out, int out_size, void* d_ws, size_t ws_size,
                              hipStream_t stream)
{
  const float* IF   = (const float*)d_in[0];   // [10,64,64,64,8]
  const float* BG   = (const float*)d_in[1];   // [10,128,128,64]
  const float* BBOX = (const float*)d_in[2];   // [10,4,8]
  const float* w1i = (const float*)d_in[4];
  const float* b1i = (const float*)d_in[5];
  const float* w2i = (const float*)d_in[6];
  const float* b2i = (const float*)d_in[7];
  const float* w1b = (const float*)d_in[8];
  const float* b1b = (const float*)d_in[9];
  const float* w2b = (const float*)d_in[10];
  const float* b2b = (const float*)d_in[11];
  const int* objn  = (const int*)d_in[12];
  float* out = (float*)d_out;

  char* wsb = (char*)d_ws;
  unsigned short* wBi3 = (unsigned short*)(wsb);              // 221,184 B
  unsigned short* wBb3 = (unsigned short*)(wsb + 221184);     // 221,184 B
  float* instw = (float*)(wsb + 442368);                      // 1,310,720 B
  float* bgw   = (float*)(wsb + 1753088);                     // 655,360 B
  float* TIF   = (float*)(wsb + 2408448);                     // 41,943,040 B
  float* h1i   = (float*)(wsb + 44351488);                    // 41,943,040 B -> 86,294,528 B (proven)
  float* h1g   = out + 5242880;                               // d_out upper half (scratch)

  prep_w32<<<144, 256, 0, stream>>>(w1i, wBi3);
  prep_w32<<<144, 256, 0, stream>>>(w1b, wBb3);

  for (int hh = 0; hh < 2; ++hh) {
    tr_if<<<5120, 256, 0, stream>>>(IF + (size_t)hh * 10485760, TIF);
    conv1_m<<<960, 256, 0, stream>>>(TIF, BG, wBi3, wBb3, b1i, b1b, h1i, h1g, hh);
    conv2_m<<<960, 256, 0, stream>>>(h1i, h1g, w2i, w2b, b2i, b2b, instw, bgw, hh);
    compose_v4<<<20480, 256, 0, stream>>>(TIF, BG, BBOX, objn, instw, bgw, out, hh);
  }
}

// Round 15
// 406.731 us; speedup vs baseline: 1.1934x; 1.1934x over previous
//
#include <hip/hip_runtime.h>
#include <cstdint>
#include <cstddef>

// B=10, Hi=Wi=64, C=64, M=8, Hb=Wb=128, U=64.
// Pipeline per b-half: tr_if -> conv1_m (round-12 proven: 16x16x32 MFMA,
// 3-way bf16 split, 2-pass 76KB LDS) -> conv2_m (NEW: c-contiguous padded
// LDS + float4 reads, 4x fewer LDS instructions) -> compose_v4.
// h1g lives in d_out's upper half (scratch until compose overwrites).

typedef __attribute__((ext_vector_type(8))) short short8;
typedef __attribute__((ext_vector_type(4))) float f32x4;

__device__ __forceinline__ unsigned short f2bf(float x) {
  union { float f; unsigned int u; } v; v.f = x;
  unsigned int r = (v.u + 0x7FFFu + ((v.u >> 16) & 1u)) >> 16;  // RNE
  return (unsigned short)r;
}
__device__ __forceinline__ float bf2f(unsigned short h) {
  union { unsigned int u; float f; } v; v.u = ((unsigned int)h) << 16;
  return v.f;
}
__device__ __forceinline__ void split3(float v, unsigned short& h,
                                       unsigned short& m, unsigned short& l) {
  h = f2bf(v);
  float r1 = v - bf2f(h);
  m = f2bf(r1);
  float r2 = r1 - bf2f(m);
  l = f2bf(r2);
}

// ---------------------------------------------------------------------------
// prep_w3: w [3,3,64,64] HWIO fp32 -> 3 bf16 fragment-ordered planes (36864
// elems apart): wB[s][((kc*4+ut)*64+lane)*8+i], k=kc*32+(lane>>4)*8+i,
// k9=k>>6, c=k&63, u=ut*16+(lane&15).  (verified rounds 5-12)
// ---------------------------------------------------------------------------
__global__ void prep_w3(const float* __restrict__ w, unsigned short* __restrict__ wB)
{
  int idx = blockIdx.x * 256 + threadIdx.x;
  if (idx >= 18 * 4 * 64 * 8) return;
  int i = idx & 7;
  int lane = (idx >> 3) & 63;
  int ut = (idx >> 9) & 3;
  int kc = idx >> 11;
  int k = kc * 32 + (lane >> 4) * 8 + i;
  int u = ut * 16 + (lane & 15);
  int k9 = k >> 6, c = k & 63;
  float v = w[((size_t)(k9 * 64 + c)) * 64 + u];
  unsigned short h, m, l;
  split3(v, h, m, l);
  wB[idx] = h;
  wB[36864 + idx] = m;
  wB[73728 + idx] = l;
}

// ---------------------------------------------------------------------------
// tr_if: IF half (5 b's) [b,y,x,c,m] -> TIF [img=bb*8+m][y][x][c] fp32.
// (proven rounds 3/11/12)
// ---------------------------------------------------------------------------
__global__ __launch_bounds__(256) void tr_if(const float* __restrict__ IFh,
                                             float* __restrict__ TIF)
{
  const int idx = blockIdx.x * 256 + threadIdx.x;   // 5*64*64*64 = 1,310,720
  const int c = idx & 63;
  const int x = (idx >> 6) & 63;
  const int y = (idx >> 12) & 63;
  const int bb = idx >> 18;
  const float* p = IFh + (size_t)idx * 8;
  float4 v0 = *(const float4*)p;
  float4 v1 = *(const float4*)(p + 4);
  float mv[8] = {v0.x, v0.y, v0.z, v0.w, v1.x, v1.y, v1.z, v1.w};
  #pragma unroll
  for (int m = 0; m < 8; ++m)
    TIF[((size_t)(bb * 8 + m) * 4096 + y * 64 + x) * 64 + c] = mv[m];
}

// ---------------------------------------------------------------------------
// conv1_m: merged instance+bg conv1 for one half (hh = 0/1). Grid = 960.
// ROUND-12 PROVEN BODY: 16x16x32 MFMA, 2 channel-half passes, LDS
// [pl][r][c8][xi] 76KB, 6-product split, product-outer/pxt-inner order.
// ---------------------------------------------------------------------------
__global__ __launch_bounds__(256, 2) void conv1_m(const float* __restrict__ TIF,
    const float* __restrict__ BG,
    const unsigned short* __restrict__ wBi, const unsigned short* __restrict__ wBb,
    const float* __restrict__ b1i, const float* __restrict__ b1b,
    float* __restrict__ h1i, float* __restrict__ h1g, int hh)
{
  __shared__ __align__(16) char lds[76032];   // 3 * 25344

  const int tid = threadIdx.x;
  const int bid = blockIdx.x;
  const bool inst = (bid < 640);

  int H, W, imgL, xt, rg;
  const unsigned short* wB;
  const float* bias;
  const float* srcimg;
  float* dst;
  if (inst) {
    H = 64; W = 64;
    imgL = bid >> 4; rg = bid & 15; xt = 0;
    wB = wBi; bias = b1i; dst = h1i;
    srcimg = TIF + (size_t)imgL * 262144;
  } else {
    const int bb = bid - 640;
    H = 128; W = 128;
    xt = bb & 1;
    const int t2 = bb >> 1;
    rg = t2 & 31; imgL = t2 >> 5;
    wB = wBb; bias = b1b; dst = h1g;
    srcimg = BG + (size_t)(hh * 5 + imgL) * 1048576;
  }
  const int yb = rg << 2;
  const int xb = xt << 6;
  const int wave = tid >> 6, lane = tid & 63;
  const int mrow = lane & 15, g = lane >> 4;

  f32x4 z = {0.f, 0.f, 0.f, 0.f};
  f32x4 acc[4][4];   // [pxt][ut]
  #pragma unroll
  for (int i = 0; i < 4; ++i)
    #pragma unroll
    for (int j = 0; j < 4; ++j)
      acc[i][j] = z;

  const short8* wBp = (const short8*)wB;   // plane stride 4608 short8

  for (int cc = 0; cc < 2; ++cc) {
    if (cc) __syncthreads();
    // ---- stage + split: rows yb-1..yb+4, x xb-1..xb+64, 32-ch half
    for (int e = tid; e < 1584; e += 256) {
      const int c8 = e & 3;
      const int q = e >> 2;
      const int xi = q % 66;
      const int r = q / 66;
      const int gy = yb + r - 1;
      const int gx = xb + xi - 1;
      float v[8] = {0.f, 0.f, 0.f, 0.f, 0.f, 0.f, 0.f, 0.f};
      if (gy >= 0 && gy < H && gx >= 0 && gx < W) {
        const float* p = srcimg + ((size_t)gy * W + gx) * 64 + cc * 32 + c8 * 8;
        float4 a = *(const float4*)p;
        float4 bq = *(const float4*)(p + 4);
        v[0] = a.x; v[1] = a.y; v[2] = a.z; v[3] = a.w;
        v[4] = bq.x; v[5] = bq.y; v[6] = bq.z; v[7] = bq.w;
      }
      short8 ph, pm, pl;
      #pragma unroll
      for (int j = 0; j < 8; ++j) {
        unsigned short h2, mi, l2;
        split3(v[j], h2, mi, l2);
        ph[j] = (short)h2; pm[j] = (short)mi; pl[j] = (short)l2;
      }
      const int wbase = (r * 4 + c8) * 1056 + xi * 16;
      *(short8*)&lds[wbase] = ph;
      *(short8*)&lds[wbase + 25344] = pm;
      *(short8*)&lds[wbase + 50688] = pl;
    }
    __syncthreads();

    // ---- K-loop over 9 taps (kc = 2*tap + cc)
    for (int tap = 0; tap < 9; ++tap) {
      const int dy = tap / 3, dx = tap % 3;
      const int kc = tap * 2 + cc;
      short8 a[4][3];
      #pragma unroll
      for (int pxt = 0; pxt < 4; ++pxt) {
        const int abase = ((wave + dy) * 4 + g) * 1056 + (pxt * 16 + mrow + dx) * 16;
        #pragma unroll
        for (int pl = 0; pl < 3; ++pl)
          a[pxt][pl] = *(const short8*)&lds[abase + pl * 25344];
      }
      #pragma unroll
      for (int ut = 0; ut < 4; ++ut) {
        const int bi = (kc * 4 + ut) * 64 + lane;
        short8 bfr[3];
        bfr[0] = wBp[bi];
        bfr[1] = wBp[4608 + bi];
        bfr[2] = wBp[9216 + bi];
        // products in per-acc order: (a0,b0)(a0,b1)(a1,b0)(a0,b2)(a2,b0)(a1,b1)
        #pragma unroll
        for (int p = 0; p < 6; ++p) {
          const int PA[6] = {0, 0, 1, 0, 2, 1};
          const int PB[6] = {0, 1, 0, 2, 0, 1};
          const int pa = PA[p], pb = PB[p];
          #pragma unroll
          for (int pxt = 0; pxt < 4; ++pxt)
            acc[pxt][ut] = __builtin_amdgcn_mfma_f32_16x16x32_bf16(
                a[pxt][pa], bfr[pb], acc[pxt][ut], 0, 0, 0);
        }
      }
    }
  }

  // ---- epilogue: D row=(lane>>4)*4+r (=px), col=lane&15 (=u); y = yb+wave
  const int y = yb + wave;
  #pragma unroll
  for (int ut = 0; ut < 4; ++ut) {
    const int u = ut * 16 + mrow;
    const float bv = bias[u];
    #pragma unroll
    for (int pxt = 0; pxt < 4; ++pxt) {
      #pragma unroll
      for (int r = 0; r < 4; ++r) {
        const int px = xb + pxt * 16 + g * 4 + r;
        dst[((size_t)(imgL * H + y) * W + px) * 64 + u] = fmaxf(acc[pxt][ut][r] + bv, 0.f);
      }
    }
  }
}

// ---------------------------------------------------------------------------
// conv2_m v2: merged instance+bg conv2 for one half. Grid = 960.
// NEW: c-contiguous padded LDS tile s[yy][xx][36] (stride 36 -> balanced
// banks, 16B-aligned quads); input + weights read as float4 -> 288 b128
// LDS reads per px instead of 1152 b32. fp32 math, quad-major accumulation.
// ---------------------------------------------------------------------------
__global__ __launch_bounds__(256) void conv2_m(const float* __restrict__ h1i,
    const float* __restrict__ h1g,
    const float* __restrict__ w2i, const float* __restrict__ w2b,
    const float* __restrict__ b2i, const float* __restrict__ b2b,
    float* __restrict__ instw, float* __restrict__ bgw, int hh)
{
  __shared__ __align__(16) float s[18 * 18 * 36];   // 46,656 B
  __shared__ __align__(16) float wsm[576];

  const int tid = threadIdx.x;
  const int bid = blockIdx.x;
  const bool inst = (bid < 640);

  int H, W, n, xt, yt;
  const float* hsrc;
  const float* w2;
  const float* b2;
  float* dst;
  if (inst) {
    H = 64; W = 64;
    n = bid >> 4;
    const int t = bid & 15;
    xt = t & 3; yt = t >> 2;
    hsrc = h1i; w2 = w2i; b2 = b2i;
    dst = instw + (size_t)(hh * 40 + n) * 4096;
  } else {
    const int bb = bid - 640;
    H = 128; W = 128;
    n = bb >> 6;
    const int t = bb & 63;
    xt = t & 7; yt = t >> 3;
    hsrc = h1g; w2 = w2b; b2 = b2b;
    dst = bgw + (size_t)(hh * 5 + n) * 16384;
  }
  const int xb = xt << 4, yb = yt << 4;
  const int tx = tid & 15, ty = tid >> 4;

  for (int e = tid; e < 576; e += 256) wsm[e] = w2[e];

  float acc = 0.f;
  for (int cc = 0; cc < 2; ++cc) {
    const int c0 = cc << 5;
    if (cc) __syncthreads();
    // ---- stage: 18x18 halo tile, 32-ch half, c-contiguous (coalesced reads)
    for (int e = tid; e < 18 * 18 * 32; e += 256) {
      int c = e & 31;
      int p = e >> 5;
      int xx = p % 18;
      int yy = p / 18;
      int gy = yb + yy - 1, gx = xb + xx - 1;
      float v = 0.f;
      if (gy >= 0 && gy < H && gx >= 0 && gx < W)
        v = hsrc[((size_t)(n * H + gy) * W + gx) * 64 + c0 + c];
      s[(yy * 18 + xx) * 36 + c] = v;
    }
    __syncthreads();
    // ---- compute: 8 quads of 4 ch, float4 LDS reads for input and weights
    #pragma unroll
    for (int cq = 0; cq < 8; ++cq) {
      float4 wr[9];
      #pragma unroll
      for (int t = 0; t < 9; ++t)
        wr[t] = *(const float4*)&wsm[t * 64 + c0 + cq * 4];
      #pragma unroll
      for (int dy = 0; dy < 3; ++dy) {
        #pragma unroll
        for (int dx = 0; dx < 3; ++dx) {
          float4 iv = *(const float4*)&s[((ty + dy) * 18 + tx + dx) * 36 + cq * 4];
          float4 wv = wr[dy * 3 + dx];
          acc += iv.x * wv.x;
          acc += iv.y * wv.y;
          acc += iv.z * wv.z;
          acc += iv.w * wv.w;
        }
      }
    }
  }
  dst[(size_t)(yb + ty) * W + xb + tx] = fmaxf(acc + b2[0], 0.f);
}

// ---------------------------------------------------------------------------
// compose_v4: wave = 1 pixel; phase 0 = per-m param chains on lanes 0..7
// (LDS table); phase 1 = coalesced taps from TIF + wave-uniform skip. (proven)
// ---------------------------------------------------------------------------
__global__ __launch_bounds__(256) void compose_v4(const float* __restrict__ TIF,
    const float* __restrict__ bg, const float* __restrict__ bbox,
    const int* __restrict__ objn, const float* __restrict__ instw,
    const float* __restrict__ bgw, float* __restrict__ out, int hh)
{
  __shared__ __align__(16) float P[4][8][8];

  const int tid = threadIdx.x;
  const int lane = tid & 63;
  const int wave = tid >> 6;
  const int c = lane;
  const int pid = hh * 81920 + blockIdx.x * 4 + wave;
  const int b = pid >> 14;
  const int rem = pid & 16383;
  const int hhp = rem >> 7;
  const int www = rem & 127;

  if (lane < 8) {
    const int m = lane;
    const float y0b = bbox[b * 32 + m];
    const float y1b = bbox[b * 32 + 8 + m];
    const float x0b = bbox[b * 32 + 16 + m];
    const float x1b = bbox[b * 32 + 24 + m];
    const float ysz = floorf(128.f * (y1b - y0b));
    const float xsz = floorf(128.f * (x1b - x0b));
    const float yf = floorf(128.f * y0b);
    const float xf = floorf(128.f * x0b);
    const float ly = (float)hhp - yf;
    const float lx = (float)www - xf;
    const bool valid = (m < objn[b]) && (ly >= 0.f) && (ly < ysz)
                       && (lx >= 0.f) && (lx < xsz);
    float sy = (ly + 0.5f) * 64.f / fmaxf(ysz, 1.f) - 0.5f;
    float sx = (lx + 0.5f) * 64.f / fmaxf(xsz, 1.f) - 0.5f;
    sy = fminf(fmaxf(sy, 0.f), 63.f);
    sx = fminf(fmaxf(sx, 0.f), 63.f);
    const int y0i = (int)floorf(sy);
    const int x0i = (int)floorf(sx);
    const int y1i = min(y0i + 1, 63);
    const int x1i = min(x0i + 1, 63);
    const float wy = sy - (float)y0i;
    const float wx = sx - (float)x0i;
    const float omwx = 1.f - wx, omwy = 1.f - wy;

    const float* iw = instw + (size_t)(b * 8 + m) * 4096;
    const float v00 = iw[y0i * 64 + x0i];
    const float v01 = iw[y0i * 64 + x1i];
    const float v10 = iw[y1i * 64 + x0i];
    const float v11 = iw[y1i * 64 + x1i];
    const float rwv = (v00 * omwx + v01 * wx) * omwy + (v10 * omwx + v11 * wx) * wy;
    const bool on = valid && (rwv > 0.f);
    const float e = on ? expf(rwv) : 0.f;

    P[wave][m][0] = e;
    P[wave][m][1] = wx;
    P[wave][m][2] = wy;
    P[wave][m][3] = (float)(y0i * 4096 + x0i * 64);
    P[wave][m][4] = (float)(y0i * 4096 + x1i * 64);
    P[wave][m][5] = (float)(y1i * 4096 + x0i * 64);
    P[wave][m][6] = (float)(y1i * 4096 + x1i * 64);
    P[wave][m][7] = 0.f;
  }
  __syncthreads();

  const float ebg = expf(bgw[pid]);
  const float bgc = bg[(size_t)pid * 64 + c];
  float denom = ebg;
  float acc = ebg * bgc;
  const float* fb = TIF + (size_t)(b - hh * 5) * 8 * 262144 + c;

  #pragma unroll
  for (int m = 0; m < 8; ++m) {
    const float4 pa = *(const float4*)&P[wave][m][0];
    const float4 pb = *(const float4*)&P[wave][m][4];
    const float e = pa.x;
    denom += e;
    if (e != 0.f) {
      const float* fm = fb + (size_t)m * 262144;
      const float t00 = fm[(int)pa.w];
      const float t01 = fm[(int)pb.x];
      const float t10 = fm[(int)pb.y];
      const float t11 = fm[(int)pb.z];
      const float wx = pa.y, wy = pa.z;
      const float omwx = 1.f - wx, omwy = 1.f - wy;
      const float bil = (t00 * omwx + t01 * wx) * omwy + (t10 * omwx + t11 * wx) * wy;
      acc += e * bil;
    }
  }
  out[(size_t)pid * 64 + c] = acc / denom;
}

// ---------------------------------------------------------------------------
extern "C" void kernel_launch(void* const* d_in, const int* in_sizes, int n_in,
                              void* d_out, int out_size, void* d_ws, size_t ws_size,
                              hipStream_t stream)
{
  const float* IF   = (const float*)d_in[0];   // [10,64,64,64,8]
  const float* BG   = (const float*)d_in[1];   // [10,128,128,64]
  const float* BBOX = (const float*)d_in[2];   // [10,4,8]
  const float* w1i = (const float*)d_in[4];
  const float* b1i = (const float*)d_in[5];
  const float* w2i = (const float*)d_in[6];
  const float* b2i = (const float*)d_in[7];
  const float* w1b = (const float*)d_in[8];
  const float* b1b = (const float*)d_in[9];
  const float* w2b = (const float*)d_in[10];
  const float* b2b = (const float*)d_in[11];
  const int* objn  = (const int*)d_in[12];
  float* out = (float*)d_out;

  char* wsb = (char*)d_ws;
  unsigned short* wBi3 = (unsigned short*)(wsb);              // 221,184 B
  unsigned short* wBb3 = (unsigned short*)(wsb + 221184);     // 221,184 B
  float* instw = (float*)(wsb + 442368);                      // 1,310,720 B
  float* bgw   = (float*)(wsb + 1753088);                     // 655,360 B
  float* TIF   = (float*)(wsb + 2408448);                     // 41,943,040 B
  float* h1i   = (float*)(wsb + 44351488);                    // 41,943,040 B -> 86,294,528 B (proven)
  float* h1g   = out + 5242880;                               // d_out upper half (scratch)

  prep_w3<<<144, 256, 0, stream>>>(w1i, wBi3);
  prep_w3<<<144, 256, 0, stream>>>(w1b, wBb3);

  for (int hh = 0; hh < 2; ++hh) {
    tr_if<<<5120, 256, 0, stream>>>(IF + (size_t)hh * 10485760, TIF);
    conv1_m<<<960, 256, 0, stream>>>(TIF, BG, wBi3, wBb3, b1i, b1b, h1i, h1g, hh);
    conv2_m<<<960, 256, 0, stream>>>(h1i, h1g, w2i, w2b, b2i, b2b, instw, bgw, hh);
    compose_v4<<<20480, 256, 0, stream>>>(TIF, BG, BBOX, objn, instw, bgw, out, hh);
  }
}

// Round 16
// 396.523 us; speedup vs baseline: 1.2242x; 1.0257x over previous
//
#include <hip/hip_runtime.h>
#include <hip/hip_bf16.h>
#include <cstdint>
#include <cstddef>

// B=10, Hi=Wi=64, C=64, M=8, Hb=Wb=128, U=64.
// Pipeline per b-half: tr_if -> conv1_m (16x16x32 MFMA, 3-way bf16 split,
// 2-pass 76KB LDS; THIS ROUND: HW-cvt split3 + register-prefetch of pass-1
// globals hidden under pass-0 MFMA) -> conv2_m (float4 LDS, proven r15) ->
// compose_v4. h1g lives in d_out's upper half.

typedef __attribute__((ext_vector_type(8))) short short8;
typedef __attribute__((ext_vector_type(4))) float f32x4;

__device__ __forceinline__ unsigned short f2bf(float x) {
  __hip_bfloat16 b = __float2bfloat16(x);   // HW RNE cvt (compiler packs)
  return reinterpret_cast<unsigned short&>(b);
}
__device__ __forceinline__ float bf2f(unsigned short h) {
  union { unsigned int u; float f; } v; v.u = ((unsigned int)h) << 16;
  return v.f;
}
// fp32 -> 3x bf16; exact decomposition (Sterbenz residuals) for any faithful
// rounding, so HW cvt preserves the verified numerics class.
__device__ __forceinline__ void split3(float v, unsigned short& h,
                                       unsigned short& m, unsigned short& l) {
  h = f2bf(v);
  float r1 = v - bf2f(h);
  m = f2bf(r1);
  float r2 = r1 - bf2f(m);
  l = f2bf(r2);
}

// ---------------------------------------------------------------------------
// prep_w3_2: both weight sets in one launch (grid 288). Layout verified r5-15:
// wB[s][((kc*4+ut)*64+lane)*8+i], k=kc*32+(lane>>4)*8+i, k9=k>>6, c=k&63,
// u=ut*16+(lane&15); plane stride 36864.
// ---------------------------------------------------------------------------
__global__ void prep_w3_2(const float* __restrict__ wA, const float* __restrict__ wBsrc,
                          unsigned short* __restrict__ dA, unsigned short* __restrict__ dB)
{
  int gidx = blockIdx.x * 256 + threadIdx.x;
  const float* w = (gidx < 36864) ? wA : wBsrc;
  unsigned short* d = (gidx < 36864) ? dA : dB;
  int idx = (gidx < 36864) ? gidx : gidx - 36864;
  int i = idx & 7;
  int lane = (idx >> 3) & 63;
  int ut = (idx >> 9) & 3;
  int kc = idx >> 11;
  int k = kc * 32 + (lane >> 4) * 8 + i;
  int u = ut * 16 + (lane & 15);
  int k9 = k >> 6, c = k & 63;
  float v = w[((size_t)(k9 * 64 + c)) * 64 + u];
  unsigned short h, m, l;
  split3(v, h, m, l);
  d[idx] = h;
  d[36864 + idx] = m;
  d[73728 + idx] = l;
}

// ---------------------------------------------------------------------------
// tr_if: IF half (5 b's) [b,y,x,c,m] -> TIF [img=bb*8+m][y][x][c] fp32. (proven)
// ---------------------------------------------------------------------------
__global__ __launch_bounds__(256) void tr_if(const float* __restrict__ IFh,
                                             float* __restrict__ TIF)
{
  const int idx = blockIdx.x * 256 + threadIdx.x;   // 5*64*64*64 = 1,310,720
  const int c = idx & 63;
  const int x = (idx >> 6) & 63;
  const int y = (idx >> 12) & 63;
  const int bb = idx >> 18;
  const float* p = IFh + (size_t)idx * 8;
  float4 v0 = *(const float4*)p;
  float4 v1 = *(const float4*)(p + 4);
  float mv[8] = {v0.x, v0.y, v0.z, v0.w, v1.x, v1.y, v1.z, v1.w};
  #pragma unroll
  for (int m = 0; m < 8; ++m)
    TIF[((size_t)(bb * 8 + m) * 4096 + y * 64 + x) * 64 + c] = mv[m];
}

// ---------------------------------------------------------------------------
// conv1_m: merged instance+bg conv1 for one half (hh = 0/1). Grid = 960.
// r12-proven MFMA body (16x16x32, 6-product split, product-outer/pxt-inner).
// NEW: pass-1 globals register-prefetched before the compute-0 barrier
// (T14); split3 uses HW cvt. Product order per accumulator unchanged.
// ---------------------------------------------------------------------------
__global__ __launch_bounds__(256, 2) void conv1_m(const float* __restrict__ TIF,
    const float* __restrict__ BG,
    const unsigned short* __restrict__ wBi, const unsigned short* __restrict__ wBb,
    const float* __restrict__ b1i, const float* __restrict__ b1b,
    float* __restrict__ h1i, float* __restrict__ h1g, int hh)
{
  __shared__ __align__(16) char lds[76032];   // 3 * 25344

  const int tid = threadIdx.x;
  const int bid = blockIdx.x;
  const bool inst = (bid < 640);

  int H, W, imgL, xt, rg;
  const unsigned short* wB;
  const float* bias;
  const float* srcimg;
  float* dst;
  if (inst) {
    H = 64; W = 64;
    imgL = bid >> 4; rg = bid & 15; xt = 0;
    wB = wBi; bias = b1i; dst = h1i;
    srcimg = TIF + (size_t)imgL * 262144;
  } else {
    const int bb = bid - 640;
    H = 128; W = 128;
    xt = bb & 1;
    const int t2 = bb >> 1;
    rg = t2 & 31; imgL = t2 >> 5;
    wB = wBb; bias = b1b; dst = h1g;
    srcimg = BG + (size_t)(hh * 5 + imgL) * 1048576;
  }
  const int yb = rg << 2;
  const int xb = xt << 6;
  const int wave = tid >> 6, lane = tid & 63;
  const int mrow = lane & 15, g = lane >> 4;

  f32x4 z = {0.f, 0.f, 0.f, 0.f};
  f32x4 acc[4][4];   // [pxt][ut]
  #pragma unroll
  for (int i = 0; i < 4; ++i)
    #pragma unroll
    for (int j = 0; j < 4; ++j)
      acc[i][j] = z;

  const short8* wBp = (const short8*)wB;   // plane stride 4608 short8

  // ---- stage pass 0 (c 0..31) directly to LDS
  for (int e = tid; e < 1584; e += 256) {
    const int c8 = e & 3;
    const int q = e >> 2;
    const int xi = q % 66;
    const int r = q / 66;
    const int gy = yb + r - 1;
    const int gx = xb + xi - 1;
    float v[8] = {0.f, 0.f, 0.f, 0.f, 0.f, 0.f, 0.f, 0.f};
    if (gy >= 0 && gy < H && gx >= 0 && gx < W) {
      const float* p = srcimg + ((size_t)gy * W + gx) * 64 + c8 * 8;
      float4 a = *(const float4*)p;
      float4 bq = *(const float4*)(p + 4);
      v[0] = a.x; v[1] = a.y; v[2] = a.z; v[3] = a.w;
      v[4] = bq.x; v[5] = bq.y; v[6] = bq.z; v[7] = bq.w;
    }
    short8 ph, pm, pl;
    #pragma unroll
    for (int j = 0; j < 8; ++j) {
      unsigned short h2, mi, l2;
      split3(v[j], h2, mi, l2);
      ph[j] = (short)h2; pm[j] = (short)mi; pl[j] = (short)l2;
    }
    const int wbase = (r * 4 + c8) * 1056 + xi * 16;
    *(short8*)&lds[wbase] = ph;
    *(short8*)&lds[wbase + 25344] = pm;
    *(short8*)&lds[wbase + 50688] = pl;
  }

  // ---- prefetch pass 1 (c 32..63) into registers (static-index unroll)
  float pf[7][8];
  #pragma unroll
  for (int it = 0; it < 7; ++it) {
    const int e = tid + it * 256;
    if (e < 1584) {
      const int c8 = e & 3;
      const int q = e >> 2;
      const int xi = q % 66;
      const int r = q / 66;
      const int gy = yb + r - 1;
      const int gx = xb + xi - 1;
      float4 a = {0.f, 0.f, 0.f, 0.f}, bq = {0.f, 0.f, 0.f, 0.f};
      if (gy >= 0 && gy < H && gx >= 0 && gx < W) {
        const float* p = srcimg + ((size_t)gy * W + gx) * 64 + 32 + c8 * 8;
        a = *(const float4*)p;
        bq = *(const float4*)(p + 4);
      }
      pf[it][0] = a.x; pf[it][1] = a.y; pf[it][2] = a.z; pf[it][3] = a.w;
      pf[it][4] = bq.x; pf[it][5] = bq.y; pf[it][6] = bq.z; pf[it][7] = bq.w;
    }
  }
  __syncthreads();

  // ---- compute pass (kc = 2*tap + cc), r12-verified order
  auto compute = [&](int cc) {
    for (int tap = 0; tap < 9; ++tap) {
      const int dy = tap / 3, dx = tap % 3;
      const int kc = tap * 2 + cc;
      short8 a[4][3];
      #pragma unroll
      for (int pxt = 0; pxt < 4; ++pxt) {
        const int abase = ((wave + dy) * 4 + g) * 1056 + (pxt * 16 + mrow + dx) * 16;
        #pragma unroll
        for (int pl = 0; pl < 3; ++pl)
          a[pxt][pl] = *(const short8*)&lds[abase + pl * 25344];
      }
      #pragma unroll
      for (int ut = 0; ut < 4; ++ut) {
        const int bi = (kc * 4 + ut) * 64 + lane;
        short8 bfr[3];
        bfr[0] = wBp[bi];
        bfr[1] = wBp[4608 + bi];
        bfr[2] = wBp[9216 + bi];
        // per-acc product order: (a0,b0)(a0,b1)(a1,b0)(a0,b2)(a2,b0)(a1,b1)
        #pragma unroll
        for (int p = 0; p < 6; ++p) {
          const int PA[6] = {0, 0, 1, 0, 2, 1};
          const int PB[6] = {0, 1, 0, 2, 0, 1};
          const int pa = PA[p], pb = PB[p];
          #pragma unroll
          for (int pxt = 0; pxt < 4; ++pxt)
            acc[pxt][ut] = __builtin_amdgcn_mfma_f32_16x16x32_bf16(
                a[pxt][pa], bfr[pb], acc[pxt][ut], 0, 0, 0);
        }
      }
    }
  };

  compute(0);
  __syncthreads();   // WAR: all reads of pass-0 LDS done

  // ---- write pass 1 from registers (loads already landed under compute 0)
  #pragma unroll
  for (int it = 0; it < 7; ++it) {
    const int e = tid + it * 256;
    if (e < 1584) {
      const int c8 = e & 3;
      const int q = e >> 2;
      const int xi = q % 66;
      const int r = q / 66;
      short8 ph, pm, pl;
      #pragma unroll
      for (int j = 0; j < 8; ++j) {
        unsigned short h2, mi, l2;
        split3(pf[it][j], h2, mi, l2);
        ph[j] = (short)h2; pm[j] = (short)mi; pl[j] = (short)l2;
      }
      const int wbase = (r * 4 + c8) * 1056 + xi * 16;
      *(short8*)&lds[wbase] = ph;
      *(short8*)&lds[wbase + 25344] = pm;
      *(short8*)&lds[wbase + 50688] = pl;
    }
  }
  __syncthreads();

  compute(1);

  // ---- epilogue: D row=(lane>>4)*4+r (=px), col=lane&15 (=u); y = yb+wave
  const int y = yb + wave;
  #pragma unroll
  for (int ut = 0; ut < 4; ++ut) {
    const int u = ut * 16 + mrow;
    const float bv = bias[u];
    #pragma unroll
    for (int pxt = 0; pxt < 4; ++pxt) {
      #pragma unroll
      for (int r = 0; r < 4; ++r) {
        const int px = xb + pxt * 16 + g * 4 + r;
        dst[((size_t)(imgL * H + y) * W + px) * 64 + u] = fmaxf(acc[pxt][ut][r] + bv, 0.f);
      }
    }
  }
}

// ---------------------------------------------------------------------------
// conv2_m: merged instance+bg conv2 for one half. Grid = 960. (proven r15:
// c-contiguous padded LDS s[yy][xx][36], float4 reads)
// ---------------------------------------------------------------------------
__global__ __launch_bounds__(256) void conv2_m(const float* __restrict__ h1i,
    const float* __restrict__ h1g,
    const float* __restrict__ w2i, const float* __restrict__ w2b,
    const float* __restrict__ b2i, const float* __restrict__ b2b,
    float* __restrict__ instw, float* __restrict__ bgw, int hh)
{
  __shared__ __align__(16) float s[18 * 18 * 36];   // 46,656 B
  __shared__ __align__(16) float wsm[576];

  const int tid = threadIdx.x;
  const int bid = blockIdx.x;
  const bool inst = (bid < 640);

  int H, W, n, xt, yt;
  const float* hsrc;
  const float* w2;
  const float* b2;
  float* dst;
  if (inst) {
    H = 64; W = 64;
    n = bid >> 4;
    const int t = bid & 15;
    xt = t & 3; yt = t >> 2;
    hsrc = h1i; w2 = w2i; b2 = b2i;
    dst = instw + (size_t)(hh * 40 + n) * 4096;
  } else {
    const int bb = bid - 640;
    H = 128; W = 128;
    n = bb >> 6;
    const int t = bb & 63;
    xt = t & 7; yt = t >> 3;
    hsrc = h1g; w2 = w2b; b2 = b2b;
    dst = bgw + (size_t)(hh * 5 + n) * 16384;
  }
  const int xb = xt << 4, yb = yt << 4;
  const int tx = tid & 15, ty = tid >> 4;

  for (int e = tid; e < 576; e += 256) wsm[e] = w2[e];

  float acc = 0.f;
  for (int cc = 0; cc < 2; ++cc) {
    const int c0 = cc << 5;
    if (cc) __syncthreads();
    for (int e = tid; e < 18 * 18 * 32; e += 256) {
      int c = e & 31;
      int p = e >> 5;
      int xx = p % 18;
      int yy = p / 18;
      int gy = yb + yy - 1, gx = xb + xx - 1;
      float v = 0.f;
      if (gy >= 0 && gy < H && gx >= 0 && gx < W)
        v = hsrc[((size_t)(n * H + gy) * W + gx) * 64 + c0 + c];
      s[(yy * 18 + xx) * 36 + c] = v;
    }
    __syncthreads();
    #pragma unroll
    for (int cq = 0; cq < 8; ++cq) {
      float4 wr[9];
      #pragma unroll
      for (int t = 0; t < 9; ++t)
        wr[t] = *(const float4*)&wsm[t * 64 + c0 + cq * 4];
      #pragma unroll
      for (int dy = 0; dy < 3; ++dy) {
        #pragma unroll
        for (int dx = 0; dx < 3; ++dx) {
          float4 iv = *(const float4*)&s[((ty + dy) * 18 + tx + dx) * 36 + cq * 4];
          float4 wv = wr[dy * 3 + dx];
          acc += iv.x * wv.x;
          acc += iv.y * wv.y;
          acc += iv.z * wv.z;
          acc += iv.w * wv.w;
        }
      }
    }
  }
  dst[(size_t)(yb + ty) * W + xb + tx] = fmaxf(acc + b2[0], 0.f);
}

// ---------------------------------------------------------------------------
// compose_v4: wave = 1 pixel; phase 0 = per-m param chains on lanes 0..7
// (LDS table); phase 1 = coalesced taps from TIF + wave-uniform skip. (proven)
// ---------------------------------------------------------------------------
__global__ __launch_bounds__(256) void compose_v4(const float* __restrict__ TIF,
    const float* __restrict__ bg, const float* __restrict__ bbox,
    const int* __restrict__ objn, const float* __restrict__ instw,
    const float* __restrict__ bgw, float* __restrict__ out, int hh)
{
  __shared__ __align__(16) float P[4][8][8];

  const int tid = threadIdx.x;
  const int lane = tid & 63;
  const int wave = tid >> 6;
  const int c = lane;
  const int pid = hh * 81920 + blockIdx.x * 4 + wave;
  const int b = pid >> 14;
  const int rem = pid & 16383;
  const int hhp = rem >> 7;
  const int www = rem & 127;

  if (lane < 8) {
    const int m = lane;
    const float y0b = bbox[b * 32 + m];
    const float y1b = bbox[b * 32 + 8 + m];
    const float x0b = bbox[b * 32 + 16 + m];
    const float x1b = bbox[b * 32 + 24 + m];
    const float ysz = floorf(128.f * (y1b - y0b));
    const float xsz = floorf(128.f * (x1b - x0b));
    const float yf = floorf(128.f * y0b);
    const float xf = floorf(128.f * x0b);
    const float ly = (float)hhp - yf;
    const float lx = (float)www - xf;
    const bool valid = (m < objn[b]) && (ly >= 0.f) && (ly < ysz)
                       && (lx >= 0.f) && (lx < xsz);
    float sy = (ly + 0.5f) * 64.f / fmaxf(ysz, 1.f) - 0.5f;
    float sx = (lx + 0.5f) * 64.f / fmaxf(xsz, 1.f) - 0.5f;
    sy = fminf(fmaxf(sy, 0.f), 63.f);
    sx = fminf(fmaxf(sx, 0.f), 63.f);
    const int y0i = (int)floorf(sy);
    const int x0i = (int)floorf(sx);
    const int y1i = min(y0i + 1, 63);
    const int x1i = min(x0i + 1, 63);
    const float wy = sy - (float)y0i;
    const float wx = sx - (float)x0i;
    const float omwx = 1.f - wx, omwy = 1.f - wy;

    const float* iw = instw + (size_t)(b * 8 + m) * 4096;
    const float v00 = iw[y0i * 64 + x0i];
    const float v01 = iw[y0i * 64 + x1i];
    const float v10 = iw[y1i * 64 + x0i];
    const float v11 = iw[y1i * 64 + x1i];
    const float rwv = (v00 * omwx + v01 * wx) * omwy + (v10 * omwx + v11 * wx) * wy;
    const bool on = valid && (rwv > 0.f);
    const float e = on ? expf(rwv) : 0.f;

    P[wave][m][0] = e;
    P[wave][m][1] = wx;
    P[wave][m][2] = wy;
    P[wave][m][3] = (float)(y0i * 4096 + x0i * 64);
    P[wave][m][4] = (float)(y0i * 4096 + x1i * 64);
    P[wave][m][5] = (float)(y1i * 4096 + x0i * 64);
    P[wave][m][6] = (float)(y1i * 4096 + x1i * 64);
    P[wave][m][7] = 0.f;
  }
  __syncthreads();

  const float ebg = expf(bgw[pid]);
  const float bgc = bg[(size_t)pid * 64 + c];
  float denom = ebg;
  float acc = ebg * bgc;
  const float* fb = TIF + (size_t)(b - hh * 5) * 8 * 262144 + c;

  #pragma unroll
  for (int m = 0; m < 8; ++m) {
    const float4 pa = *(const float4*)&P[wave][m][0];
    const float4 pb = *(const float4*)&P[wave][m][4];
    const float e = pa.x;
    denom += e;
    if (e != 0.f) {
      const float* fm = fb + (size_t)m * 262144;
      const float t00 = fm[(int)pa.w];
      const float t01 = fm[(int)pb.x];
      const float t10 = fm[(int)pb.y];
      const float t11 = fm[(int)pb.z];
      const float wx = pa.y, wy = pa.z;
      const float omwx = 1.f - wx, omwy = 1.f - wy;
      const float bil = (t00 * omwx + t01 * wx) * omwy + (t10 * omwx + t11 * wx) * wy;
      acc += e * bil;
    }
  }
  out[(size_t)pid * 64 + c] = acc / denom;
}

// ---------------------------------------------------------------------------
extern "C" void kernel_launch(void* const* d_in, const int* in_sizes, int n_in,
                              void* d_out, int out_size, void* d_ws, size_t ws_size,
                              hipStream_t stream)
{
  const float* IF   = (const float*)d_in[0];   // [10,64,64,64,8]
  const float* BG   = (const float*)d_in[1];   // [10,128,128,64]
  const float* BBOX = (const float*)d_in[2];   // [10,4,8]
  const float* w1i = (const float*)d_in[4];
  const float* b1i = (const float*)d_in[5];
  const float* w2i = (const float*)d_in[6];
  const float* b2i = (const float*)d_in[7];
  const float* w1b = (const float*)d_in[8];
  const float* b1b = (const float*)d_in[9];
  const float* w2b = (const float*)d_in[10];
  const float* b2b = (const float*)d_in[11];
  const int* objn  = (const int*)d_in[12];
  float* out = (float*)d_out;

  char* wsb = (char*)d_ws;
  unsigned short* wBi3 = (unsigned short*)(wsb);              // 221,184 B
  unsigned short* wBb3 = (unsigned short*)(wsb + 221184);     // 221,184 B
  float* instw = (float*)(wsb + 442368);                      // 1,310,720 B
  float* bgw   = (float*)(wsb + 1753088);                     // 655,360 B
  float* TIF   = (float*)(wsb + 2408448);                     // 41,943,040 B
  float* h1i   = (float*)(wsb + 44351488);                    // 41,943,040 B -> 86,294,528 B (proven)
  float* h1g   = out + 5242880;                               // d_out upper half (scratch)

  prep_w3_2<<<288, 256, 0, stream>>>(w1i, w1b, wBi3, wBb3);

  for (int hh = 0; hh < 2; ++hh) {
    tr_if<<<5120, 256, 0, stream>>>(IF + (size_t)hh * 10485760, TIF);
    conv1_m<<<960, 256, 0, stream>>>(TIF, BG, wBi3, wBb3, b1i, b1b, h1i, h1g, hh);
    conv2_m<<<960, 256, 0, stream>>>(h1i, h1g, w2i, w2b, b2i, b2b, instw, bgw, hh);
    compose_v4<<<20480, 256, 0, stream>>>(TIF, BG, BBOX, objn, instw, bgw, out, hh);
  }
}